// Round 5
// baseline (11608.636 us; speedup 1.0000x reference)
//
#include <hip/hip_runtime.h>
#include <math.h>

typedef __attribute__((ext_vector_type(8))) _Float16 half8;
typedef __attribute__((ext_vector_type(4))) _Float16 half4;
typedef __attribute__((ext_vector_type(4))) float    f32x4;
typedef unsigned long long u64;

#define NSTEP 256
#define NB    1024
#define HID   256
#define BH    262144          // NB*HID
#define LK    40              // padded LDS row stride (f16 units) -> 2-way banks only
#define INV2K 4.8828125e-4f   // 1/2048

__device__ __forceinline__ float sigf(float x){ return 1.f/(1.f+expf(-x)); }
__device__ __forceinline__ void splitf(float v, _Float16& h, _Float16& l){
    h = (_Float16)v; l = (_Float16)((v - (float)h)*2048.f);
}

// agent-scope (device-coherent, L2-bypassing) atomic accessors
__device__ __forceinline__ u64 ald64(const void* p){
    return __hip_atomic_load((const u64*)p, __ATOMIC_RELAXED, __HIP_MEMORY_SCOPE_AGENT);
}
__device__ __forceinline__ void ast64(void* p, u64 v){
    __hip_atomic_store((u64*)p, v, __ATOMIC_RELAXED, __HIP_MEMORY_SCOPE_AGENT);
}
__device__ __forceinline__ unsigned ald32(const void* p){
    return __hip_atomic_load((const unsigned*)p, __ATOMIC_RELAXED, __HIP_MEMORY_SCOPE_AGENT);
}
__device__ __forceinline__ void ast32(void* p, unsigned v){
    __hip_atomic_store((unsigned*)p, v, __ATOMIC_RELAXED, __HIP_MEMORY_SCOPE_AGENT);
}

union H4U { half4 v; u64 u; };

// ---------------------------------------------------------------------------
// Weight pre-split (transpose + fp16 hi/lo)
// ---------------------------------------------------------------------------
__global__ __launch_bounds__(256)
void wsplit_k(const float* __restrict__ s0, const float* __restrict__ s1,
              const float* __restrict__ s2, int K, int N, int ldn,
              int kb1, int kb2, _Float16* __restrict__ oh, _Float16* __restrict__ ol)
{
    int idx = blockIdx.x*256 + threadIdx.x;
    if (idx >= N*K) return;
    int n = idx / K, k = idx - n*K;
    const float* s = (k < kb1) ? &s0[(size_t)k*ldn]
                   : (k < kb2) ? &s1[(size_t)(k-kb1)*ldn]
                               : &s2[(size_t)(k-kb2)*ldn];
    float v = s[n];
    _Float16 h, l; splitf(v, h, l);
    oh[idx] = h; ol[idx] = l;
}

__global__ void wz_k(const float* __restrict__ W01, const float* __restrict__ U21,
                     const float* __restrict__ U11, float* __restrict__ wz)
{
    int k = blockIdx.x*256 + threadIdx.x;
    if (k >= 768) return;
    wz[k] = (k < 256) ? W01[(size_t)k*1025 + 1024]
          : (k < 512) ? U21[(size_t)(k-256)*1025 + 1024]
                      : U11[(size_t)(k-512)*1025 + 1024];
}

__global__ __launch_bounds__(256)
void init_k(_Float16* h1h, _Float16* h1l, unsigned* z0)
{
    int i = blockIdx.x*256 + threadIdx.x;
    if (i < BH) { h1h[i]=(_Float16)0.f; h1l[i]=(_Float16)0.f; }
    if (i < NB) z0[i] = 1u;
}

__global__ __launch_bounds__(256)
void zslot_k(_Float16* sh, _Float16* sl)     // zero slot 0 (h2 init)
{
    int i = blockIdx.x*256 + threadIdx.x;    // BH/4 threads
    *(half4*)&sh[(size_t)i*4] = half4{};
    *(half4*)&sl[(size_t)i*4] = half4{};
}

// ---------------------------------------------------------------------------
// Tiled parallel GEMM (encoder/head), unchanged from the passing round-4 code.
// ---------------------------------------------------------------------------
template<int AIN, int AOUT, int NCOL>
__global__ __launch_bounds__(256)
void gemm_t(const float* __restrict__ Af,
            const _Float16* __restrict__ Ah_, const _Float16* __restrict__ Al_,
            const _Float16* __restrict__ Bh_, const _Float16* __restrict__ Bl_,
            const float* __restrict__ bias,
            _Float16* __restrict__ Oh, _Float16* __restrict__ Ol,
            float* __restrict__ Of)
{
    constexpr int NT = 8;     // K = 256
    __shared__ __align__(16) char smem[40960];

    const int tid  = threadIdx.x;
    const size_t R0 = (size_t)blockIdx.x*64;
    const int C0   = blockIdx.y*64;
    const int rh   = (tid>>6)&1, ch = tid>>7;
    const int lane = tid&63, lr = lane&15, kq = (lane>>4)<<3;
    const int arow = tid>>2, seg = tid&3;
    const size_t abase = (R0+arow)*256 + seg*8;
    const size_t wbase = (size_t)(C0 + (tid>>2))*256 + seg*8;

    f32x4 am[2][2], ax[2][2];
#pragma unroll
    for (int r=0;r<2;++r)
#pragma unroll
        for (int c=0;c<2;++c){ am[r][c]=(f32x4)0.f; ax[r][c]=(f32x4)0.f; }

    half8 rah, ral, rwh, rwl;
    auto load_tile = [&](int k0, half8& ah, half8& al, half8& wh, half8& wl) {
        if (AIN == 0) {
            float4 a0 = *(const float4*)(Af + abase + k0);
            float4 a1 = *(const float4*)(Af + abase + k0 + 4);
            float av[8] = {a0.x,a0.y,a0.z,a0.w,a1.x,a1.y,a1.z,a1.w};
#pragma unroll
            for (int i=0;i<8;++i){ _Float16 h,l; splitf(av[i],h,l); ah[i]=h; al[i]=l; }
        } else {
            ah = *(const half8*)(Ah_ + abase + k0);
            al = *(const half8*)(Al_ + abase + k0);
        }
        wh = *(const half8*)(Bh_ + wbase + k0);
        wl = *(const half8*)(Bl_ + wbase + k0);
    };
    auto store_tile = [&](int buf) {
        char* bs = smem + buf*20480;
        *(half8*)((_Float16*)(bs        ) + arow*LK + seg*8) = rah;
        *(half8*)((_Float16*)(bs +  5120) + arow*LK + seg*8) = ral;
        *(half8*)((_Float16*)(bs + 10240) + (tid>>2)*LK + seg*8) = rwh;
        *(half8*)((_Float16*)(bs + 15360) + (tid>>2)*LK + seg*8) = rwl;
    };

    load_tile(0, rah, ral, rwh, rwl);
    store_tile(0);

#pragma unroll 2
    for (int kb = 0; kb < NT; ++kb) {
        const int buf = kb & 1;
        half8 nah, nal, nwh, nwl;
        if (kb+1 < NT) load_tile((kb+1)*32, nah, nal, nwh, nwl);
        __syncthreads();
        const char* bs = smem + buf*20480;
        const _Float16* LAh = (const _Float16*)bs;
        const _Float16* LAl = (const _Float16*)(bs +  5120);
        const _Float16* LBh = (const _Float16*)(bs + 10240);
        const _Float16* LBl = (const _Float16*)(bs + 15360);
        half8 fah[2], fal[2], fbh[2], fbl[2];
#pragma unroll
        for (int rf=0;rf<2;++rf) {
            fah[rf] = *(const half8*)(LAh + (rh*32+rf*16+lr)*LK + kq);
            fal[rf] = *(const half8*)(LAl + (rh*32+rf*16+lr)*LK + kq);
        }
#pragma unroll
        for (int cf=0;cf<2;++cf) {
            fbh[cf] = *(const half8*)(LBh + (ch*32+cf*16+lr)*LK + kq);
            fbl[cf] = *(const half8*)(LBl + (ch*32+cf*16+lr)*LK + kq);
        }
#pragma unroll
        for (int cf=0;cf<2;++cf)
#pragma unroll
            for (int rf=0;rf<2;++rf) {
                am[rf][cf] = __builtin_amdgcn_mfma_f32_16x16x32_f16(fah[rf], fbh[cf], am[rf][cf],0,0,0);
                ax[rf][cf] = __builtin_amdgcn_mfma_f32_16x16x32_f16(fah[rf], fbl[cf], ax[rf][cf],0,0,0);
                ax[rf][cf] = __builtin_amdgcn_mfma_f32_16x16x32_f16(fal[rf], fbh[cf], ax[rf][cf],0,0,0);
            }
        if (kb+1 < NT) {
            rah=nah; ral=nal; rwh=nwh; rwl=nwl;
            store_tile((kb+1)&1);
        }
    }

#pragma unroll
    for (int cf=0;cf<2;++cf) {
        int col = C0 + ch*32 + cf*16 + lr;
        float bcol = bias[col];
#pragma unroll
        for (int rf=0;rf<2;++rf)
#pragma unroll
            for (int q=0;q<4;++q) {
                size_t row = R0 + rh*32 + rf*16 + ((lane>>4)<<2) + q;
                float v = am[rf][cf][q] + ax[rf][cf][q]*INV2K + bcol;
                if (AOUT == 0) {
                    v = fmaxf(v, 0.f);
                    _Float16 h,l; splitf(v,h,l);
                    Oh[row*NCOL + col] = h;
                    Ol[row*NCOL + col] = l;
                } else {
                    Of[row*NCOL + col] = tanhf(v);
                }
            }
    }
}

// ---------------------------------------------------------------------------
// Persistent recurrence. 256 blocks x 512 thr. Block (rp = bid>>4, cs = bid&15):
// rows rp*64..+64, hidden cols cs*16..+16 (x4 gates = 64 fs cols).
// 16 independent row-panel pipelines; per-panel 16-block L3-atomic barriers
// (release-add + relaxed spin; NO acquire -> no L2 invalidate -> W stays in L2).
// State (h1, h2/emb slots, z) via agent-scope relaxed atomics (sc1, L2-bypass).
// c1/c2 in registers across all 256 steps.
// ---------------------------------------------------------------------------
struct PArgs {
    _Float16 *SH, *SL;                       // slots: h2(t)=slot t; xe(t)=slot t+1 -> emb(t)
    const _Float16 *W1h, *W1l, *W2h, *W2l;
    const float *b1, *b2, *wz, *noise;
    _Float16 *h1h0, *h1h1, *h1l0, *h1l1;
    unsigned *z0, *z1;
    unsigned *ctr;                           // [512 phases][16 rp], zeroed per call
};

__device__ __forceinline__ void rp_barrier(unsigned* c, int tid)
{
    __syncthreads();   // drains vmcnt: all block stores completed at coherence point
    if (tid == 0) {
        __hip_atomic_fetch_add(c, 1u, __ATOMIC_RELEASE, __HIP_MEMORY_SCOPE_AGENT);
        while (__hip_atomic_load(c, __ATOMIC_RELAXED, __HIP_MEMORY_SCOPE_AGENT) < 16u)
            __builtin_amdgcn_s_sleep(2);
    }
    __syncthreads();
}

__global__ __launch_bounds__(512, 1)
void hm_pers_k(PArgs a)
{
    __shared__ __align__(16) char smem[61440];   // 3 staging bufs x 20 KB
    float* ex = (float*)smem;                    // epilogue overlay [4][64][16] f32

    const int tid = threadIdx.x, wv = tid>>6, lane = tid&63;
    const int cs = blockIdx.x & 15, rp = blockIdx.x >> 4;   // cs -> stable XCD (bid%8)
    const int g  = wv>>1, rh = wv&1;
    const int lr = lane&15, kq = (lane>>4)<<3;
    const int R0 = rp*64, j0 = cs*16;
    const int srow = tid>>3, skq = (tid&7)*4;    // staging: 64 rows x 8 k-segs of 4
    const int gcol = (srow>>4)*256 + j0 + (srow&15);
    const size_t w1base = (size_t)gcol*768 + skq;
    const size_t w2base = (size_t)gcol*512 + skq;
    const size_t arbase = (size_t)(R0+srow)*HID;
    const float bv1 = a.b1[g*256 + j0 + lr];
    const float bv2 = a.b2[g*256 + j0 + lr];
    const bool do_z = (cs == 0);

    const int urow = (tid & 255)>>2, ujj = (tid&3)*4;       // update mapping (tid<256)
    const size_t ubase = (size_t)(R0+urow)*HID + j0 + ujj;
    float c1s[4] = {0,0,0,0}, c2s[4] = {0,0,0,0};

    for (int t = 0; t < NSTEP; ++t) {
        _Float16* h1hc = (t&1) ? a.h1h1 : a.h1h0;
        _Float16* h1lc = (t&1) ? a.h1l1 : a.h1l0;
        _Float16* h1hn = (t&1) ? a.h1h0 : a.h1h1;
        _Float16* h1ln = (t&1) ? a.h1l0 : a.h1l1;
        unsigned* zc = (t&1) ? a.z1 : a.z0;
        unsigned* zn = (t&1) ? a.z0 : a.z1;
        _Float16* slotc_h = a.SH + (size_t)t*BH;
        _Float16* slotc_l = a.SL + (size_t)t*BH;
        _Float16* slotn_h = a.SH + (size_t)(t+1)*BH;
        _Float16* slotn_l = a.SL + (size_t)(t+1)*BH;

        // ================ phase 1: fs1 = [h1 | z*h2 | xe] @ W1 ==============
        const unsigned zrv = ald32(&zc[R0+srow]);
        f32x4 am[2], ax[2];
        am[0]=(f32x4)0.f; am[1]=(f32x4)0.f; ax[0]=(f32x4)0.f; ax[1]=(f32x4)0.f;
        float zacc = 0.f;
        u64 Ah_[2], Al_[2], Wh_[2], Wl_[2];

        auto p1_load = [&](int kt, int s){
            int kg = kt*32 + skq;
            u64 hv, lv;
            if (kg < 256)      { hv = ald64(h1hc + arbase + kg);
                                 lv = ald64(h1lc + arbase + kg); }
            else if (kg < 512) {
                if (zrv) { hv = ald64(slotc_h + arbase + (kg-256));
                           lv = ald64(slotc_l + arbase + (kg-256)); }
                else     { hv = 0; lv = 0; }
            } else             { hv = *(const u64*)(slotn_h + arbase + (kg-512));
                                 lv = *(const u64*)(slotn_l + arbase + (kg-512)); }
            Ah_[s]=hv; Al_[s]=lv;
            Wh_[s] = *(const u64*)(a.W1h + w1base + (size_t)kt*32);
            Wl_[s] = *(const u64*)(a.W1l + w1base + (size_t)kt*32);
        };
        auto p2_load = [&](int kt, int s, unsigned zrv2){
            int kg = kt*32 + skq;
            u64 hv, lv;
            if (kg < 256)      { hv = ald64(slotc_h + arbase + kg);
                                 lv = ald64(slotc_l + arbase + kg); }
            else {
                if (zrv2) { hv = ald64(h1hn + arbase + (kg-256));
                            lv = ald64(h1ln + arbase + (kg-256)); }
                else      { hv = 0; lv = 0; }
            }
            Ah_[s]=hv; Al_[s]=lv;
            Wh_[s] = *(const u64*)(a.W2h + w2base + (size_t)kt*32);
            Wl_[s] = *(const u64*)(a.W2l + w2base + (size_t)kt*32);
        };
        auto stg = [&](int buf, int s){
            char* bs = smem + buf*20480;
            *(u64*)((_Float16*)(bs        ) + srow*LK + skq) = Ah_[s];
            *(u64*)((_Float16*)(bs +  5120) + srow*LK + skq) = Al_[s];
            *(u64*)((_Float16*)(bs + 10240) + srow*LK + skq) = Wh_[s];
            *(u64*)((_Float16*)(bs + 15360) + srow*LK + skq) = Wl_[s];
        };
        auto cmp = [&](int buf, int kt, bool dz){
            const char* bs = smem + buf*20480;
            const _Float16* LAh = (const _Float16*)bs;
            const _Float16* LAl = (const _Float16*)(bs +  5120);
            const _Float16* LBh = (const _Float16*)(bs + 10240);
            const _Float16* LBl = (const _Float16*)(bs + 15360);
            half8 fbh = *(const half8*)(LBh + (g*16+lr)*LK + kq);
            half8 fbl = *(const half8*)(LBl + (g*16+lr)*LK + kq);
#pragma unroll
            for (int rf=0; rf<2; ++rf) {
                half8 fah = *(const half8*)(LAh + (rh*32+rf*16+lr)*LK + kq);
                half8 fal = *(const half8*)(LAl + (rh*32+rf*16+lr)*LK + kq);
                am[rf] = __builtin_amdgcn_mfma_f32_16x16x32_f16(fah, fbh, am[rf],0,0,0);
                ax[rf] = __builtin_amdgcn_mfma_f32_16x16x32_f16(fah, fbl, ax[rf],0,0,0);
                ax[rf] = __builtin_amdgcn_mfma_f32_16x16x32_f16(fal, fbh, ax[rf],0,0,0);
            }
            if (dz) {
#pragma unroll
                for (int i=0;i<4;++i) {
                    float av = (float)LAh[srow*LK + skq + i]
                             + (float)LAl[srow*LK + skq + i]*INV2K;
                    zacc = fmaf(av, a.wz[kt*32 + skq + i], zacc);
                }
            }
        };

        p1_load(0,0); p1_load(1,1);
        stg(0,0);
#pragma unroll
        for (int kt = 0; kt < 24; ++kt) {
            if (kt+2 < 24) p1_load(kt+2, kt&1);
            __syncthreads();
            cmp(kt%3, kt, do_z);
            if (kt+1 < 24) stg((kt+1)%3, (kt+1)&1);
        }
        __syncthreads();

        // fs1 -> ex (activated)
#pragma unroll
        for (int rf=0; rf<2; ++rf)
#pragma unroll
            for (int q=0;q<4;++q) {
                float v = am[rf][q] + ax[rf][q]*INV2K + bv1;
                v = (g<3) ? sigf(v) : tanhf(v);
                int row = rh*32 + rf*16 + ((lane>>4)<<2) + q;
                ex[(g*64+row)*16 + lr] = v;
            }
        // z (exact fp32 dot, reduce 8 segs/row)
        if (do_z) {
            float s = zacc;
            s += __shfl_xor(s, 1);
            s += __shfl_xor(s, 2);
            s += __shfl_xor(s, 4);
            if ((tid&7) == 0) {
                float fsz = s + a.b1[1024];
                float zh = fminf(fmaxf((0.1f*fsz + 1.f)*0.5f, 0.05f), 0.95f);
                ast32(&zn[R0+srow],
                      (a.noise[(size_t)t*NB + R0+srow] < zh) ? 1u : 0u);
            }
        }
        __syncthreads();
        if (tid < 256) {
            half4 hh, hl;
#pragma unroll
            for (int q=0;q<4;++q) {
                float f0 = ex[(0*64+urow)*16 + ujj + q];
                float i0 = ex[(1*64+urow)*16 + ujj + q];
                float o0 = ex[(2*64+urow)*16 + ujj + q];
                float g0 = ex[(3*64+urow)*16 + ujj + q];
                float cn = f0*c1s[q] + i0*g0;
                c1s[q] = cn;
                float hv = o0*tanhf(cn);
                _Float16 h,l; splitf(hv,h,l); hh[q]=h; hl[q]=l;
            }
            H4U ph, pl; ph.v = hh; pl.v = hl;
            ast64(h1hn + ubase, ph.u);
            ast64(h1ln + ubase, pl.u);
        }
        rp_barrier(a.ctr + (size_t)(t*2)*16 + rp, tid);

        // ================ phase 2: fs2 = [h2 | z1n*h1n] @ W2 ================
        const unsigned zrv2 = ald32(&zn[R0+srow]);
        am[0]=(f32x4)0.f; am[1]=(f32x4)0.f; ax[0]=(f32x4)0.f; ax[1]=(f32x4)0.f;

        p2_load(0,0,zrv2); p2_load(1,1,zrv2);
        stg(0,0);
#pragma unroll
        for (int kt = 0; kt < 16; ++kt) {
            if (kt+2 < 16) p2_load(kt+2, kt&1, zrv2);
            __syncthreads();
            cmp(kt%3, kt, false);
            if (kt+1 < 16) stg((kt+1)%3, (kt+1)&1);
        }
        __syncthreads();

#pragma unroll
        for (int rf=0; rf<2; ++rf)
#pragma unroll
            for (int q=0;q<4;++q) {
                float v = am[rf][q] + ax[rf][q]*INV2K + bv2;
                v = (g<3) ? sigf(v) : tanhf(v);
                int row = rh*32 + rf*16 + ((lane>>4)<<2) + q;
                ex[(g*64+row)*16 + lr] = v;
            }
        __syncthreads();
        if (tid < 256) {
            unsigned zun = ald32(&zn[R0+urow]);
            half4 hh, hl;
#pragma unroll
            for (int q=0;q<4;++q) {
                float f0 = ex[(0*64+urow)*16 + ujj + q];
                float i0 = ex[(1*64+urow)*16 + ujj + q];
                float o0 = ex[(2*64+urow)*16 + ujj + q];
                float g0 = ex[(3*64+urow)*16 + ujj + q];
                float cn = zun ? (f0*c2s[q] + i0*g0) : c2s[q];
                c2s[q] = cn;
                float hv = o0*tanhf(cn);
                _Float16 h,l; splitf(hv,h,l); hh[q]=h; hl[q]=l;
            }
            H4U ph, pl; ph.v = hh; pl.v = hl;
            ast64(slotn_h + ubase, ph.u);   // h2(t+1) == emb(t)
            ast64(slotn_l + ubase, pl.u);
        }
        rp_barrier(a.ctr + (size_t)(t*2+1)*16 + rp, tid);
    }
}

// ---------------------------------------------------------------------------
extern "C" void kernel_launch(void* const* d_in, const int* in_sizes, int n_in,
                              void* d_out, int out_size, void* d_ws, size_t ws_size,
                              hipStream_t stream)
{
    const float* x     = (const float*)d_in[0];
    const float* n1    = (const float*)d_in[1];
    const float* We1   = (const float*)d_in[3];
    const float* be1   = (const float*)d_in[4];
    const float* We2   = (const float*)d_in[5];
    const float* be2   = (const float*)d_in[6];
    const float* U11_1 = (const float*)d_in[7];
    const float* U21_1 = (const float*)d_in[8];
    const float* W01_1 = (const float*)d_in[9];
    const float* b1    = (const float*)d_in[10];
    const float* U11_2 = (const float*)d_in[11];
    const float* W01_2 = (const float*)d_in[12];
    const float* b2    = (const float*)d_in[13];
    const float* Wh    = (const float*)d_in[14];
    const float* bh    = (const float*)d_in[15];
    const float* Wp    = (const float*)d_in[16];
    const float* bp_   = (const float*)d_in[17];
    float* out = (float*)d_out;

    char* p = (char*)d_ws;
    auto alloc = [&](size_t bytes){ char* q = p; p += (bytes + 255) & ~(size_t)255; return q; };
    _Float16* SH   = (_Float16*)alloc((size_t)(NSTEP+1)*BH*2);
    _Float16* SL   = (_Float16*)alloc((size_t)(NSTEP+1)*BH*2);
    _Float16* TmpH = (_Float16*)alloc((size_t)32*BH*2);
    _Float16* TmpL = (_Float16*)alloc((size_t)32*BH*2);
    _Float16* Wt1h = (_Float16*)alloc((size_t)1024*768*2);
    _Float16* Wt1l = (_Float16*)alloc((size_t)1024*768*2);
    _Float16* Wt2h = (_Float16*)alloc((size_t)1024*512*2);
    _Float16* Wt2l = (_Float16*)alloc((size_t)1024*512*2);
    _Float16* We1h = (_Float16*)alloc(256*256*2);
    _Float16* We1l = (_Float16*)alloc(256*256*2);
    _Float16* We2h = (_Float16*)alloc(256*256*2);
    _Float16* We2l = (_Float16*)alloc(256*256*2);
    _Float16* Whh  = (_Float16*)alloc(256*256*2);
    _Float16* Whl  = (_Float16*)alloc(256*256*2);
    _Float16* Wph  = (_Float16*)alloc(64*256*2);
    _Float16* Wpl  = (_Float16*)alloc(64*256*2);
    float*    wz1  = (float*)alloc(768*4);
    _Float16* h1h0 = (_Float16*)alloc((size_t)BH*2);
    _Float16* h1h1 = (_Float16*)alloc((size_t)BH*2);
    _Float16* h1l0 = (_Float16*)alloc((size_t)BH*2);
    _Float16* h1l1 = (_Float16*)alloc((size_t)BH*2);
    unsigned* z0   = (unsigned*)alloc(NB*4);
    unsigned* z1b  = (unsigned*)alloc(NB*4);
    unsigned* ctr  = (unsigned*)alloc((size_t)NSTEP*2*16*4);
    if (ws_size < (size_t)(p - (char*)d_ws)) return;

    // ---- prep ----
    wsplit_k<<<dim3(3072), 256, 0, stream>>>(W01_1, U21_1, U11_1, 768, 1024, 1025, 256, 512, Wt1h, Wt1l);
    wsplit_k<<<dim3(2048), 256, 0, stream>>>(W01_2, U11_2, nullptr, 512, 1024, 1025, 256, 512, Wt2h, Wt2l);
    wsplit_k<<<dim3(256),  256, 0, stream>>>(We1, nullptr, nullptr, 256, 256, 256, 256, 256, We1h, We1l);
    wsplit_k<<<dim3(256),  256, 0, stream>>>(We2, nullptr, nullptr, 256, 256, 256, 256, 256, We2h, We2l);
    wsplit_k<<<dim3(256),  256, 0, stream>>>(Wh,  nullptr, nullptr, 256, 256, 256, 256, 256, Whh,  Whl);
    wsplit_k<<<dim3(64),   256, 0, stream>>>(Wp,  nullptr, nullptr, 256, 64, 64, 256, 256, Wph, Wpl);
    wz_k<<<dim3(3), 256, 0, stream>>>(W01_1, U21_1, U11_1, wz1);
    init_k<<<dim3(1024), 256, 0, stream>>>(h1h0, h1l0, z0);
    hipMemsetAsync(ctr, 0, (size_t)NSTEP*2*16*4, stream);

    // ---- encoder (chunked 8 x 32 steps): xe(t) -> slot t+1 ----
    for (int c = 0; c < 8; ++c) {
        size_t ro = (size_t)c*32*BH;
        gemm_t<0,0,256><<<dim3(512,4), 256, 0, stream>>>(
            x + ro, nullptr, nullptr, We1h, We1l, be1, TmpH, TmpL, nullptr);
        gemm_t<1,0,256><<<dim3(512,4), 256, 0, stream>>>(
            nullptr, TmpH, TmpL, We2h, We2l, be2, SH + BH + ro, SL + BH + ro, nullptr);
    }
    zslot_k<<<dim3(256), 256, 0, stream>>>(SH, SL);   // h2(-1) = 0 in slot 0

    // ---- recurrence: one persistent kernel, per-panel barriers ----
    PArgs pa;
    pa.SH = SH; pa.SL = SL;
    pa.W1h = Wt1h; pa.W1l = Wt1l; pa.W2h = Wt2h; pa.W2l = Wt2l;
    pa.b1 = b1; pa.b2 = b2; pa.wz = wz1; pa.noise = n1;
    pa.h1h0 = h1h0; pa.h1h1 = h1h1; pa.h1l0 = h1l0; pa.h1l1 = h1l1;
    pa.z0 = z0; pa.z1 = z1b; pa.ctr = ctr;
    void* kargs[] = { (void*)&pa };
    hipLaunchCooperativeKernel((const void*)hm_pers_k, dim3(256), dim3(512),
                               kargs, 0, stream);

    // ---- head (chunked): out = tanh(relu(emb@Wh+bh)@Wp+bp) ----
    for (int c = 0; c < 8; ++c) {
        size_t ro = (size_t)c*32*BH;
        gemm_t<1,0,256><<<dim3(512,4), 256, 0, stream>>>(
            nullptr, SH + BH + ro, SL + BH + ro, Whh, Whl, bh, TmpH, TmpL, nullptr);
        gemm_t<1,1,64><<<dim3(512,1), 256, 0, stream>>>(
            nullptr, TmpH, TmpL, Wph, Wpl, bp_, nullptr, nullptr,
            out + (size_t)c*32*NB*64);
    }
}

// Round 7
// 8055.695 us; speedup vs baseline: 1.4410x; 1.4410x over previous
//
#include <hip/hip_runtime.h>
#include <math.h>

typedef __attribute__((ext_vector_type(8))) _Float16 half8;
typedef __attribute__((ext_vector_type(4))) _Float16 half4;
typedef __attribute__((ext_vector_type(4))) float    f32x4;
typedef unsigned long long u64;

#define NSTEP 256
#define CH    32              // steps per persistent chunk
#define NCHUNK (NSTEP/CH)
#define NB    1024
#define HID   256
#define BH    262144          // NB*HID
#define LK    40              // padded LDS row stride (f16 units) -> 2-way banks only
#define EXS   20              // ex exchange row stride (f32) -> conflict-light
#define INV2K 4.8828125e-4f   // 1/2048
#define SEQ_SMEM 98304        // forces 1 block/CU => exactly 32 blocks/XCD

__device__ __forceinline__ float sigf(float x){ return 1.f/(1.f+expf(-x)); }
__device__ __forceinline__ void splitf(float v, _Float16& h, _Float16& l){
    h = (_Float16)v; l = (_Float16)((v - (float)h)*2048.f);
}
union H4U { half4 v; u64 u; };

// ---------------------------------------------------------------------------
// Weight pre-split (transpose + fp16 hi/lo)
// ---------------------------------------------------------------------------
__global__ __launch_bounds__(256)
void wsplit_k(const float* __restrict__ s0, const float* __restrict__ s1,
              const float* __restrict__ s2, int K, int N, int ldn,
              int kb1, int kb2, _Float16* __restrict__ oh, _Float16* __restrict__ ol)
{
    int idx = blockIdx.x*256 + threadIdx.x;
    if (idx >= N*K) return;
    int n = idx / K, k = idx - n*K;
    const float* s = (k < kb1) ? &s0[(size_t)k*ldn]
                   : (k < kb2) ? &s1[(size_t)(k-kb1)*ldn]
                               : &s2[(size_t)(k-kb2)*ldn];
    float v = s[n];
    _Float16 h, l; splitf(v, h, l);
    oh[idx] = h; ol[idx] = l;
}

__global__ void wz_k(const float* __restrict__ W01, const float* __restrict__ U21,
                     const float* __restrict__ U11, float* __restrict__ wz)
{
    int k = blockIdx.x*256 + threadIdx.x;
    if (k >= 768) return;
    wz[k] = (k < 256) ? W01[(size_t)k*1025 + 1024]
          : (k < 512) ? U21[(size_t)(k-256)*1025 + 1024]
                      : U11[(size_t)(k-512)*1025 + 1024];
}

__global__ __launch_bounds__(256)
void init_k(_Float16* h1H, _Float16* h1L, _Float16* h2H, _Float16* h2L,
            float* c1g, float* c2g, unsigned* zr)
{
    int i = blockIdx.x*256 + threadIdx.x;   // BH threads
    h1H[i] = (_Float16)0.f; h1L[i] = (_Float16)0.f;
    h2H[i] = (_Float16)0.f; h2L[i] = (_Float16)0.f;
    c1g[i] = 0.f; c2g[i] = 0.f;
    if (i < NB) zr[i] = 1u;
}

// ---------------------------------------------------------------------------
// Tiled parallel GEMM (encoder/head) — unchanged from passing round-4 code.
// ---------------------------------------------------------------------------
template<int AIN, int AOUT, int NCOL>
__global__ __launch_bounds__(256)
void gemm_t(const float* __restrict__ Af,
            const _Float16* __restrict__ Ah_, const _Float16* __restrict__ Al_,
            const _Float16* __restrict__ Bh_, const _Float16* __restrict__ Bl_,
            const float* __restrict__ bias,
            _Float16* __restrict__ Oh, _Float16* __restrict__ Ol,
            float* __restrict__ Of)
{
    constexpr int NT = 8;     // K = 256
    __shared__ __align__(16) char smem[40960];

    const int tid  = threadIdx.x;
    const size_t R0 = (size_t)blockIdx.x*64;
    const int C0   = blockIdx.y*64;
    const int rh   = (tid>>6)&1, ch = tid>>7;
    const int lane = tid&63, lr = lane&15, kq = (lane>>4)<<3;
    const int arow = tid>>2, seg = tid&3;
    const size_t abase = (R0+arow)*256 + seg*8;
    const size_t wbase = (size_t)(C0 + (tid>>2))*256 + seg*8;

    f32x4 am[2][2], ax[2][2];
#pragma unroll
    for (int r=0;r<2;++r)
#pragma unroll
        for (int c=0;c<2;++c){ am[r][c]=(f32x4)0.f; ax[r][c]=(f32x4)0.f; }

    half8 rah, ral, rwh, rwl;
    auto load_tile = [&](int k0, half8& ah, half8& al, half8& wh, half8& wl) {
        if (AIN == 0) {
            float4 a0 = *(const float4*)(Af + abase + k0);
            float4 a1 = *(const float4*)(Af + abase + k0 + 4);
            float av[8] = {a0.x,a0.y,a0.z,a0.w,a1.x,a1.y,a1.z,a1.w};
#pragma unroll
            for (int i=0;i<8;++i){ _Float16 h,l; splitf(av[i],h,l); ah[i]=h; al[i]=l; }
        } else {
            ah = *(const half8*)(Ah_ + abase + k0);
            al = *(const half8*)(Al_ + abase + k0);
        }
        wh = *(const half8*)(Bh_ + wbase + k0);
        wl = *(const half8*)(Bl_ + wbase + k0);
    };
    auto store_tile = [&](int buf) {
        char* bs = smem + buf*20480;
        *(half8*)((_Float16*)(bs        ) + arow*LK + seg*8) = rah;
        *(half8*)((_Float16*)(bs +  5120) + arow*LK + seg*8) = ral;
        *(half8*)((_Float16*)(bs + 10240) + (tid>>2)*LK + seg*8) = rwh;
        *(half8*)((_Float16*)(bs + 15360) + (tid>>2)*LK + seg*8) = rwl;
    };

    load_tile(0, rah, ral, rwh, rwl);
    store_tile(0);

#pragma unroll 2
    for (int kb = 0; kb < NT; ++kb) {
        const int buf = kb & 1;
        half8 nah, nal, nwh, nwl;
        if (kb+1 < NT) load_tile((kb+1)*32, nah, nal, nwh, nwl);
        __syncthreads();
        const char* bs = smem + buf*20480;
        const _Float16* LAh = (const _Float16*)bs;
        const _Float16* LAl = (const _Float16*)(bs +  5120);
        const _Float16* LBh = (const _Float16*)(bs + 10240);
        const _Float16* LBl = (const _Float16*)(bs + 15360);
        half8 fah[2], fal[2], fbh[2], fbl[2];
#pragma unroll
        for (int rf=0;rf<2;++rf) {
            fah[rf] = *(const half8*)(LAh + (rh*32+rf*16+lr)*LK + kq);
            fal[rf] = *(const half8*)(LAl + (rh*32+rf*16+lr)*LK + kq);
        }
#pragma unroll
        for (int cf=0;cf<2;++cf) {
            fbh[cf] = *(const half8*)(LBh + (ch*32+cf*16+lr)*LK + kq);
            fbl[cf] = *(const half8*)(LBl + (ch*32+cf*16+lr)*LK + kq);
        }
#pragma unroll
        for (int cf=0;cf<2;++cf)
#pragma unroll
            for (int rf=0;rf<2;++rf) {
                am[rf][cf] = __builtin_amdgcn_mfma_f32_16x16x32_f16(fah[rf], fbh[cf], am[rf][cf],0,0,0);
                ax[rf][cf] = __builtin_amdgcn_mfma_f32_16x16x32_f16(fah[rf], fbl[cf], ax[rf][cf],0,0,0);
                ax[rf][cf] = __builtin_amdgcn_mfma_f32_16x16x32_f16(fal[rf], fbh[cf], ax[rf][cf],0,0,0);
            }
        if (kb+1 < NT) {
            rah=nah; ral=nal; rwh=nwh; rwl=nwl;
            store_tile((kb+1)&1);
        }
    }

#pragma unroll
    for (int cf=0;cf<2;++cf) {
        int col = C0 + ch*32 + cf*16 + lr;
        float bcol = bias[col];
#pragma unroll
        for (int rf=0;rf<2;++rf)
#pragma unroll
            for (int q=0;q<4;++q) {
                size_t row = R0 + rh*32 + rf*16 + ((lane>>4)<<2) + q;
                float v = am[rf][cf][q] + ax[rf][cf][q]*INV2K + bcol;
                if (AOUT == 0) {
                    v = fmaxf(v, 0.f);
                    _Float16 h,l; splitf(v,h,l);
                    Oh[row*NCOL + col] = h;
                    Ol[row*NCOL + col] = l;
                } else {
                    Of[row*NCOL + col] = tanhf(v);
                }
            }
    }
}

// ---------------------------------------------------------------------------
// Persistent recurrence chunk (CH steps). 256 blocks x 512 thr, 1 block/CU
// (forced by 96KB LDS => exactly 32 blocks per XCD when launch succeeds).
// Panel/cs from HW_REG_XCC_ID + per-XCD ticket: a panel's 16 blocks share one
// XCD -> one L2. State: write-once rings, PLAIN cached loads/stores (L2-local).
// Barrier: __syncthreads (vmcnt drain) + AGENT-scope relaxed atomic + bounded
// AGENT-scope spin (round-5-proven intrinsics; no hand-rolled cache bits).
// ---------------------------------------------------------------------------
struct PArgs {
    const _Float16 *XeH, *XeL;         // [NSTEP][BH] read-only
    _Float16 *EmH, *EmL;               // [NSTEP][BH] emb out
    const _Float16 *W1h, *W1l, *W2h, *W2l;
    const float *b1, *b2, *wz, *noise;
    _Float16 *h1rH, *h1rL, *h2rH, *h2rL;  // rings [(CH+1)][BH]
    unsigned *zr;                          // ring  [(CH+1)][NB]
    float *c1g, *c2g;                      // [BH]
    unsigned *ctr;                         // [NCHUNK][CH*2][16] write-once
    unsigned *tick;                        // [NCHUNK][8]
    int chunk;
};

__device__ __forceinline__ void xbarrier(unsigned* c, int tid)
{
    __syncthreads();   // compiler emits s_waitcnt vmcnt(0) lgkmcnt(0) before s_barrier
    if (tid == 0) {
        __hip_atomic_fetch_add(c, 1u, __ATOMIC_RELAXED, __HIP_MEMORY_SCOPE_AGENT);
        int guard = 0;
        while (__hip_atomic_load(c, __ATOMIC_RELAXED, __HIP_MEMORY_SCOPE_AGENT) < 16u
               && guard < (1<<19)) {        // bounded: pathology -> wrong answer, not hang
            __builtin_amdgcn_s_sleep(2);
            ++guard;
        }
    }
    __syncthreads();
}

__global__ __launch_bounds__(512, 1)
void hm_pers_k(PArgs a)
{
    extern __shared__ __align__(16) char smem[];
    float* ex = (float*)smem;                  // [4][64][EXS] f32, overlays buf0

    const int tid = threadIdx.x, wv = tid>>6, lane = tid&63;

    // ---- XCD-grounded panel/cs assignment ----
    unsigned* pan_sh = (unsigned*)(smem + 61440);
    if (tid == 0) {
        unsigned xcc;
        asm volatile("s_getreg_b32 %0, hwreg(HW_REG_XCC_ID)" : "=s"(xcc));
        xcc &= 7u;
        unsigned slot = __hip_atomic_fetch_add(a.tick + a.chunk*8 + xcc, 1u,
                          __ATOMIC_RELAXED, __HIP_MEMORY_SCOPE_AGENT);
        pan_sh[0] = (xcc + 8u*(slot>>4)) & 15u;
        pan_sh[1] = slot & 15u;
    }
    __syncthreads();
    const int panel = pan_sh[0], cs = pan_sh[1];

    const int g  = wv>>1, rh = wv&1;
    const int lr = lane&15, kq = (lane>>4)<<3;
    const int R0 = panel*64, j0 = cs*16;
    const int srow = tid>>3, skq = (tid&7)*4;      // staging: 64 rows x 8 segs of 4
    const int gcol = (srow>>4)*256 + j0 + (srow&15);
    const size_t w1base = (size_t)gcol*768 + skq;
    const size_t w2base = (size_t)gcol*512 + skq;
    const size_t arbase = (size_t)(R0+srow)*HID;
    const float bv1 = a.b1[g*256 + j0 + lr];
    const float bv2 = a.b2[g*256 + j0 + lr];
    const bool do_z = (cs == 0);

    const int urow = (tid & 255)>>2, ujj = (tid&3)*4;   // update mapping (tid<256)
    const size_t ubase = (size_t)(R0+urow)*HID + j0 + ujj;

    float c1s[4], c2s[4];
    if (tid < 256) {
        float4 cv1 = *(const float4*)(a.c1g + ubase);
        float4 cv2 = *(const float4*)(a.c2g + ubase);
        c1s[0]=cv1.x; c1s[1]=cv1.y; c1s[2]=cv1.z; c1s[3]=cv1.w;
        c2s[0]=cv2.x; c2s[1]=cv2.y; c2s[2]=cv2.z; c2s[3]=cv2.w;
    }

#pragma unroll 1
    for (int s = 0; s < CH; ++s) {
        const int t = a.chunk*CH + s;
        const _Float16* h1cH = a.h1rH + (size_t)s*BH;
        const _Float16* h1cL = a.h1rL + (size_t)s*BH;
        _Float16*       h1nH = a.h1rH + (size_t)(s+1)*BH;
        _Float16*       h1nL = a.h1rL + (size_t)(s+1)*BH;
        const _Float16* h2cH = a.h2rH + (size_t)s*BH;
        const _Float16* h2cL = a.h2rL + (size_t)s*BH;
        _Float16*       h2nH = a.h2rH + (size_t)(s+1)*BH;
        _Float16*       h2nL = a.h2rL + (size_t)(s+1)*BH;
        const unsigned* zc = a.zr + (size_t)s*NB;
        unsigned*       zn = a.zr + (size_t)(s+1)*NB;
        const _Float16* xeh = a.XeH + (size_t)t*BH;
        const _Float16* xel = a.XeL + (size_t)t*BH;

        // ================ phase 1: fs1 = [h1 | z*h2 | xe] @ W1 ==============
        const unsigned zrv = zc[R0+srow];
        f32x4 am[2], ax[2];
        am[0]=(f32x4)0.f; am[1]=(f32x4)0.f; ax[0]=(f32x4)0.f; ax[1]=(f32x4)0.f;
        float zacc = 0.f;
        u64 Ah_[2], Al_[2], Wh_[2], Wl_[2];

        auto p1_load = [&](int kt, int sl){
            int kg = kt*32 + skq;
            u64 hv, lv;
            if (kg < 256)      { hv = *(const u64*)(h1cH + arbase + kg);
                                 lv = *(const u64*)(h1cL + arbase + kg); }
            else if (kg < 512) {
                if (zrv) { hv = *(const u64*)(h2cH + arbase + (kg-256));
                           lv = *(const u64*)(h2cL + arbase + (kg-256)); }
                else     { hv = 0; lv = 0; }
            } else             { hv = *(const u64*)(xeh + arbase + (kg-512));
                                 lv = *(const u64*)(xel + arbase + (kg-512)); }
            Ah_[sl]=hv; Al_[sl]=lv;
            Wh_[sl] = *(const u64*)(a.W1h + w1base + (size_t)kt*32);
            Wl_[sl] = *(const u64*)(a.W1l + w1base + (size_t)kt*32);
        };
        auto p2_load = [&](int kt, int sl, unsigned zg){
            int kg = kt*32 + skq;
            u64 hv, lv;
            if (kg < 256)      { hv = *(const u64*)(h2cH + arbase + kg);
                                 lv = *(const u64*)(h2cL + arbase + kg); }
            else {
                if (zg) { hv = *(const u64*)(h1nH + arbase + (kg-256));
                          lv = *(const u64*)(h1nL + arbase + (kg-256)); }
                else    { hv = 0; lv = 0; }
            }
            Ah_[sl]=hv; Al_[sl]=lv;
            Wh_[sl] = *(const u64*)(a.W2h + w2base + (size_t)kt*32);
            Wl_[sl] = *(const u64*)(a.W2l + w2base + (size_t)kt*32);
        };
        auto stg = [&](int buf, int sl){
            char* bs = smem + buf*20480;
            *(u64*)((_Float16*)(bs        ) + srow*LK + skq) = Ah_[sl];
            *(u64*)((_Float16*)(bs +  5120) + srow*LK + skq) = Al_[sl];
            *(u64*)((_Float16*)(bs + 10240) + srow*LK + skq) = Wh_[sl];
            *(u64*)((_Float16*)(bs + 15360) + srow*LK + skq) = Wl_[sl];
        };
        auto cmp = [&](int buf, int kt, bool dz){
            const char* bs = smem + buf*20480;
            const _Float16* LAh = (const _Float16*)bs;
            const _Float16* LAl = (const _Float16*)(bs +  5120);
            const _Float16* LBh = (const _Float16*)(bs + 10240);
            const _Float16* LBl = (const _Float16*)(bs + 15360);
            half8 fbh = *(const half8*)(LBh + (g*16+lr)*LK + kq);
            half8 fbl = *(const half8*)(LBl + (g*16+lr)*LK + kq);
#pragma unroll
            for (int rf=0; rf<2; ++rf) {
                half8 fah = *(const half8*)(LAh + (rh*32+rf*16+lr)*LK + kq);
                half8 fal = *(const half8*)(LAl + (rh*32+rf*16+lr)*LK + kq);
                am[rf] = __builtin_amdgcn_mfma_f32_16x16x32_f16(fah, fbh, am[rf],0,0,0);
                ax[rf] = __builtin_amdgcn_mfma_f32_16x16x32_f16(fah, fbl, ax[rf],0,0,0);
                ax[rf] = __builtin_amdgcn_mfma_f32_16x16x32_f16(fal, fbh, ax[rf],0,0,0);
            }
            if (dz) {
#pragma unroll
                for (int i=0;i<4;++i) {
                    float av = (float)LAh[srow*LK + skq + i]
                             + (float)LAl[srow*LK + skq + i]*INV2K;
                    zacc = fmaf(av, a.wz[kt*32 + skq + i], zacc);
                }
            }
        };

        p1_load(0,0); p1_load(1,1);
        stg(0,0);
#pragma unroll
        for (int kt = 0; kt < 24; ++kt) {
            if (kt+2 < 24) p1_load(kt+2, kt&1);
            __syncthreads();
            cmp(kt%3, kt, do_z);
            if (kt+1 < 24) stg((kt+1)%3, (kt+1)&1);
        }
        __syncthreads();

        // fs1 -> ex (activated)
#pragma unroll
        for (int rf=0; rf<2; ++rf)
#pragma unroll
            for (int q=0;q<4;++q) {
                float v = am[rf][q] + ax[rf][q]*INV2K + bv1;
                v = (g<3) ? sigf(v) : tanhf(v);
                int row = rh*32 + rf*16 + ((lane>>4)<<2) + q;
                ex[(g*64+row)*EXS + lr] = v;
            }
        if (do_z) {
            float sum = zacc;
            sum += __shfl_xor(sum, 1);
            sum += __shfl_xor(sum, 2);
            sum += __shfl_xor(sum, 4);
            if ((tid&7) == 0) {
                float fsz = sum + a.b1[1024];
                float zh = fminf(fmaxf((0.1f*fsz + 1.f)*0.5f, 0.05f), 0.95f);
                unsigned zv = (a.noise[(size_t)t*NB + R0+srow] < zh) ? 1u : 0u;
                zn[R0+srow] = zv;
                if (s == CH-1) a.zr[R0+srow] = zv;   // ring slot 0 for next chunk
            }
        }
        __syncthreads();
        if (tid < 256) {
            half4 hh, hl;
#pragma unroll
            for (int q=0;q<4;++q) {
                float f0 = ex[(0*64+urow)*EXS + ujj + q];
                float i0 = ex[(1*64+urow)*EXS + ujj + q];
                float o0 = ex[(2*64+urow)*EXS + ujj + q];
                float g0 = ex[(3*64+urow)*EXS + ujj + q];
                float cn = f0*c1s[q] + i0*g0;
                c1s[q] = cn;
                float hv = o0*tanhf(cn);
                _Float16 h,l; splitf(hv,h,l); hh[q]=h; hl[q]=l;
            }
            H4U ph_, pl_; ph_.v = hh; pl_.v = hl;
            *(u64*)(h1nH + ubase) = ph_.u;
            *(u64*)(h1nL + ubase) = pl_.u;
            if (s == CH-1) {
                *(u64*)(a.h1rH + ubase) = ph_.u;
                *(u64*)(a.h1rL + ubase) = pl_.u;
            }
        }
        xbarrier(a.ctr + ((size_t)(a.chunk*CH + s)*2 + 0)*16 + panel, tid);

        // ================ phase 2: fs2 = [h2 | z1n*h1n] @ W2 ================
        const unsigned zrv2 = zn[R0+srow];
        am[0]=(f32x4)0.f; am[1]=(f32x4)0.f; ax[0]=(f32x4)0.f; ax[1]=(f32x4)0.f;

        p2_load(0,0,zrv2); p2_load(1,1,zrv2);
        stg(0,0);
#pragma unroll
        for (int kt = 0; kt < 16; ++kt) {
            if (kt+2 < 16) p2_load(kt+2, kt&1, zrv2);
            __syncthreads();
            cmp(kt%3, kt, false);
            if (kt+1 < 16) stg((kt+1)%3, (kt+1)&1);
        }
        __syncthreads();

#pragma unroll
        for (int rf=0; rf<2; ++rf)
#pragma unroll
            for (int q=0;q<4;++q) {
                float v = am[rf][q] + ax[rf][q]*INV2K + bv2;
                v = (g<3) ? sigf(v) : tanhf(v);
                int row = rh*32 + rf*16 + ((lane>>4)<<2) + q;
                ex[(g*64+row)*EXS + lr] = v;
            }
        __syncthreads();
        if (tid < 256) {
            unsigned zun = zn[R0+urow];
            half4 hh, hl;
#pragma unroll
            for (int q=0;q<4;++q) {
                float f0 = ex[(0*64+urow)*EXS + ujj + q];
                float i0 = ex[(1*64+urow)*EXS + ujj + q];
                float o0 = ex[(2*64+urow)*EXS + ujj + q];
                float g0 = ex[(3*64+urow)*EXS + ujj + q];
                float cn = zun ? (f0*c2s[q] + i0*g0) : c2s[q];
                c2s[q] = cn;
                float hv = o0*tanhf(cn);
                _Float16 h,l; splitf(hv,h,l); hh[q]=h; hl[q]=l;
            }
            H4U ph_, pl_; ph_.v = hh; pl_.v = hl;
            *(u64*)(h2nH + ubase) = ph_.u;
            *(u64*)(h2nL + ubase) = pl_.u;
            *(u64*)(a.EmH + (size_t)t*BH + ubase) = ph_.u;
            *(u64*)(a.EmL + (size_t)t*BH + ubase) = pl_.u;
            if (s == CH-1) {
                *(u64*)(a.h2rH + ubase) = ph_.u;
                *(u64*)(a.h2rL + ubase) = pl_.u;
            }
        }
        xbarrier(a.ctr + ((size_t)(a.chunk*CH + s)*2 + 1)*16 + panel, tid);
    }

    // carry c across chunk boundary
    if (tid < 256) {
        *(float4*)(a.c1g + ubase) = float4{c1s[0],c1s[1],c1s[2],c1s[3]};
        *(float4*)(a.c2g + ubase) = float4{c2s[0],c2s[1],c2s[2],c2s[3]};
    }
}

// ---------------------------------------------------------------------------
extern "C" void kernel_launch(void* const* d_in, const int* in_sizes, int n_in,
                              void* d_out, int out_size, void* d_ws, size_t ws_size,
                              hipStream_t stream)
{
    const float* x     = (const float*)d_in[0];
    const float* n1    = (const float*)d_in[1];
    const float* We1   = (const float*)d_in[3];
    const float* be1   = (const float*)d_in[4];
    const float* We2   = (const float*)d_in[5];
    const float* be2   = (const float*)d_in[6];
    const float* U11_1 = (const float*)d_in[7];
    const float* U21_1 = (const float*)d_in[8];
    const float* W01_1 = (const float*)d_in[9];
    const float* b1    = (const float*)d_in[10];
    const float* U11_2 = (const float*)d_in[11];
    const float* W01_2 = (const float*)d_in[12];
    const float* b2    = (const float*)d_in[13];
    const float* Wh    = (const float*)d_in[14];
    const float* bh    = (const float*)d_in[15];
    const float* Wp    = (const float*)d_in[16];
    const float* bp_   = (const float*)d_in[17];
    float* out = (float*)d_out;

    char* p = (char*)d_ws;
    auto alloc = [&](size_t bytes){ char* q = p; p += (bytes + 255) & ~(size_t)255; return q; };
    _Float16* XeH  = (_Float16*)alloc((size_t)NSTEP*BH*2);
    _Float16* XeL  = (_Float16*)alloc((size_t)NSTEP*BH*2);
    _Float16* EmH  = (_Float16*)alloc((size_t)NSTEP*BH*2);
    _Float16* EmL  = (_Float16*)alloc((size_t)NSTEP*BH*2);
    _Float16* Wt1h = (_Float16*)alloc((size_t)1024*768*2);
    _Float16* Wt1l = (_Float16*)alloc((size_t)1024*768*2);
    _Float16* Wt2h = (_Float16*)alloc((size_t)1024*512*2);
    _Float16* Wt2l = (_Float16*)alloc((size_t)1024*512*2);
    _Float16* We1h = (_Float16*)alloc(256*256*2);
    _Float16* We1l = (_Float16*)alloc(256*256*2);
    _Float16* We2h = (_Float16*)alloc(256*256*2);
    _Float16* We2l = (_Float16*)alloc(256*256*2);
    _Float16* Whh  = (_Float16*)alloc(256*256*2);
    _Float16* Whl  = (_Float16*)alloc(256*256*2);
    _Float16* Wph  = (_Float16*)alloc(64*256*2);
    _Float16* Wpl  = (_Float16*)alloc(64*256*2);
    float*    wz1  = (float*)alloc(768*4);
    _Float16* h1rH = (_Float16*)alloc((size_t)(CH+1)*BH*2);
    _Float16* h1rL = (_Float16*)alloc((size_t)(CH+1)*BH*2);
    _Float16* h2rH = (_Float16*)alloc((size_t)(CH+1)*BH*2);
    _Float16* h2rL = (_Float16*)alloc((size_t)(CH+1)*BH*2);
    unsigned* zr   = (unsigned*)alloc((size_t)(CH+1)*NB*4);
    float*    c1g  = (float*)alloc((size_t)BH*4);
    float*    c2g  = (float*)alloc((size_t)BH*4);
    unsigned* ctr  = (unsigned*)alloc((size_t)NCHUNK*CH*2*16*4);
    unsigned* tick = (unsigned*)alloc((size_t)NCHUNK*8*4);
    if (ws_size < (size_t)(p - (char*)d_ws)) return;

    // encoder temp aliases Em (dead then); head temp aliases Xe (dead then)
    _Float16* TmpH = EmH; _Float16* TmpL = EmL;
    _Float16* TpH  = XeH; _Float16* TpL  = XeL;

    // ---- prep ----
    wsplit_k<<<dim3(3072), 256, 0, stream>>>(W01_1, U21_1, U11_1, 768, 1024, 1025, 256, 512, Wt1h, Wt1l);
    wsplit_k<<<dim3(2048), 256, 0, stream>>>(W01_2, U11_2, nullptr, 512, 1024, 1025, 256, 512, Wt2h, Wt2l);
    wsplit_k<<<dim3(256),  256, 0, stream>>>(We1, nullptr, nullptr, 256, 256, 256, 256, 256, We1h, We1l);
    wsplit_k<<<dim3(256),  256, 0, stream>>>(We2, nullptr, nullptr, 256, 256, 256, 256, 256, We2h, We2l);
    wsplit_k<<<dim3(256),  256, 0, stream>>>(Wh,  nullptr, nullptr, 256, 256, 256, 256, 256, Whh,  Whl);
    wsplit_k<<<dim3(64),   256, 0, stream>>>(Wp,  nullptr, nullptr, 256, 64, 64, 256, 256, Wph, Wpl);
    wz_k<<<dim3(3), 256, 0, stream>>>(W01_1, U21_1, U11_1, wz1);
    init_k<<<dim3(1024), 256, 0, stream>>>(h1rH, h1rL, h2rH, h2rL, c1g, c2g, zr);
    hipMemsetAsync(ctr, 0, (size_t)NCHUNK*CH*2*16*4, stream);
    hipMemsetAsync(tick, 0, (size_t)NCHUNK*8*4, stream);

    // ---- encoder: xe = relu(relu(x@We1)@We2) -> Xe ----
    for (int c = 0; c < 8; ++c) {
        size_t ro = (size_t)c*32*BH;
        gemm_t<0,0,256><<<dim3(512,4), 256, 0, stream>>>(
            x + ro, nullptr, nullptr, We1h, We1l, be1, TmpH, TmpL, nullptr);
        gemm_t<1,0,256><<<dim3(512,4), 256, 0, stream>>>(
            nullptr, TmpH, TmpL, We2h, We2l, be2, XeH + ro, XeL + ro, nullptr);
    }

    // ---- recurrence: 8 persistent chunks ----
    hipFuncSetAttribute((const void*)hm_pers_k, hipFuncAttributeMaxDynamicSharedMemorySize, SEQ_SMEM);
    PArgs pa;
    pa.XeH = XeH; pa.XeL = XeL; pa.EmH = EmH; pa.EmL = EmL;
    pa.W1h = Wt1h; pa.W1l = Wt1l; pa.W2h = Wt2h; pa.W2l = Wt2l;
    pa.b1 = b1; pa.b2 = b2; pa.wz = wz1; pa.noise = n1;
    pa.h1rH = h1rH; pa.h1rL = h1rL; pa.h2rH = h2rH; pa.h2rL = h2rL;
    pa.zr = zr; pa.c1g = c1g; pa.c2g = c2g; pa.ctr = ctr; pa.tick = tick;
    for (int c = 0; c < NCHUNK; ++c) {
        pa.chunk = c;
        void* kargs[] = { (void*)&pa };
        hipLaunchCooperativeKernel((const void*)hm_pers_k, dim3(256), dim3(512),
                                   kargs, SEQ_SMEM, stream);
    }

    // ---- head: out = tanh(relu(emb@Wh)@Wp) ----
    for (int c = 0; c < 8; ++c) {
        size_t ro = (size_t)c*32*BH;
        gemm_t<1,0,256><<<dim3(512,4), 256, 0, stream>>>(
            nullptr, EmH + ro, EmL + ro, Whh, Whl, bh, TpH, TpL, nullptr);
        gemm_t<1,1,64><<<dim3(512,1), 256, 0, stream>>>(
            nullptr, TpH, TpL, Wph, Wpl, bp_, nullptr, nullptr,
            out + (size_t)c*32*NB*64);
    }
}

// Round 9
// 7311.578 us; speedup vs baseline: 1.5877x; 1.1018x over previous
//
#include <hip/hip_runtime.h>
#include <math.h>

typedef __attribute__((ext_vector_type(8))) _Float16 half8;
typedef __attribute__((ext_vector_type(4))) float    f32x4;
typedef unsigned long long u64;

#define NSTEP 256
#define CH    32              // steps per persistent chunk
#define NCHUNK (NSTEP/CH)
#define NB    1024
#define HID   256
#define BH    262144          // NB*HID
#define LK    40              // A/W2 LDS row stride (f16) -> 2-way banks only
#define LK1   776             // W1 LDS row stride (f16)   -> 2-way banks only
#define INV2K 4.8828125e-4f   // 1/2048

// LDS layout (bytes)
#define W1H_OFF 0             // 32 x 776 x 2 = 49664
#define W1L_OFF 49664
#define AB_OFF  99328         // 2 bufs x (hi 10240 | lo 10240) = 40960
#define W2_OFF  140288        // 2 bufs x (hi 2560 | lo 2560)   = 10240
#define PAN_OFF 150528
#define SEQ_SMEM 150784       // forces 1 block/CU => exactly 32 blocks/XCD
#define EX_OFF  AB_OFF        // epilogue overlay [4][128][9] f32 = 18432 (fits buf0)

__device__ __forceinline__ float sigf(float x){ return 1.f/(1.f+expf(-x)); }
__device__ __forceinline__ void splitf(float v, _Float16& h, _Float16& l){
    h = (_Float16)v; l = (_Float16)((v - (float)h)*2048.f);
}
union H2U { _Float16 h[2]; unsigned u; };

// ---------------------------------------------------------------------------
// Weight pre-split (transpose + fp16 hi/lo)
// ---------------------------------------------------------------------------
__global__ __launch_bounds__(256)
void wsplit_k(const float* __restrict__ s0, const float* __restrict__ s1,
              const float* __restrict__ s2, int K, int N, int ldn,
              int kb1, int kb2, _Float16* __restrict__ oh, _Float16* __restrict__ ol)
{
    int idx = blockIdx.x*256 + threadIdx.x;
    if (idx >= N*K) return;
    int n = idx / K, k = idx - n*K;
    const float* s = (k < kb1) ? &s0[(size_t)k*ldn]
                   : (k < kb2) ? &s1[(size_t)(k-kb1)*ldn]
                               : &s2[(size_t)(k-kb2)*ldn];
    float v = s[n];
    _Float16 h, l; splitf(v, h, l);
    oh[idx] = h; ol[idx] = l;
}

__global__ void wz_k(const float* __restrict__ W01, const float* __restrict__ U21,
                     const float* __restrict__ U11, float* __restrict__ wz)
{
    int k = blockIdx.x*256 + threadIdx.x;
    if (k >= 768) return;
    wz[k] = (k < 256) ? W01[(size_t)k*1025 + 1024]
          : (k < 512) ? U21[(size_t)(k-256)*1025 + 1024]
                      : U11[(size_t)(k-512)*1025 + 1024];
}

__global__ __launch_bounds__(256)
void init_k(_Float16* h1H, _Float16* h1L, _Float16* h2H, _Float16* h2L,
            float* c1g, float* c2g, unsigned* zr)
{
    int i = blockIdx.x*256 + threadIdx.x;   // BH threads
    h1H[i] = (_Float16)0.f; h1L[i] = (_Float16)0.f;
    h2H[i] = (_Float16)0.f; h2L[i] = (_Float16)0.f;
    c1g[i] = 0.f; c2g[i] = 0.f;
    if (i < NB) zr[i] = 1u;
}

// ---------------------------------------------------------------------------
// Tiled parallel GEMM (encoder/head) — unchanged from passing round-4 code.
// ---------------------------------------------------------------------------
template<int AIN, int AOUT, int NCOL>
__global__ __launch_bounds__(256)
void gemm_t(const float* __restrict__ Af,
            const _Float16* __restrict__ Ah_, const _Float16* __restrict__ Al_,
            const _Float16* __restrict__ Bh_, const _Float16* __restrict__ Bl_,
            const float* __restrict__ bias,
            _Float16* __restrict__ Oh, _Float16* __restrict__ Ol,
            float* __restrict__ Of)
{
    constexpr int NT = 8;     // K = 256
    __shared__ __align__(16) char smem[40960];

    const int tid  = threadIdx.x;
    const size_t R0 = (size_t)blockIdx.x*64;
    const int C0   = blockIdx.y*64;
    const int rh   = (tid>>6)&1, ch = tid>>7;
    const int lane = tid&63, lr = lane&15, kq = (lane>>4)<<3;
    const int arow = tid>>2, seg = tid&3;
    const size_t abase = (R0+arow)*256 + seg*8;
    const size_t wbase = (size_t)(C0 + (tid>>2))*256 + seg*8;

    f32x4 am[2][2], ax[2][2];
#pragma unroll
    for (int r=0;r<2;++r)
#pragma unroll
        for (int c=0;c<2;++c){ am[r][c]=(f32x4)0.f; ax[r][c]=(f32x4)0.f; }

    half8 rah, ral, rwh, rwl;
    auto load_tile = [&](int k0, half8& ah, half8& al, half8& wh, half8& wl) {
        if (AIN == 0) {
            float4 a0 = *(const float4*)(Af + abase + k0);
            float4 a1 = *(const float4*)(Af + abase + k0 + 4);
            float av[8] = {a0.x,a0.y,a0.z,a0.w,a1.x,a1.y,a1.z,a1.w};
#pragma unroll
            for (int i=0;i<8;++i){ _Float16 h,l; splitf(av[i],h,l); ah[i]=h; al[i]=l; }
        } else {
            ah = *(const half8*)(Ah_ + abase + k0);
            al = *(const half8*)(Al_ + abase + k0);
        }
        wh = *(const half8*)(Bh_ + wbase + k0);
        wl = *(const half8*)(Bl_ + wbase + k0);
    };
    auto store_tile = [&](int buf) {
        char* bs = smem + buf*20480;
        *(half8*)((_Float16*)(bs        ) + arow*LK + seg*8) = rah;
        *(half8*)((_Float16*)(bs +  5120) + arow*LK + seg*8) = ral;
        *(half8*)((_Float16*)(bs + 10240) + (tid>>2)*LK + seg*8) = rwh;
        *(half8*)((_Float16*)(bs + 15360) + (tid>>2)*LK + seg*8) = rwl;
    };

    load_tile(0, rah, ral, rwh, rwl);
    store_tile(0);

#pragma unroll 2
    for (int kb = 0; kb < NT; ++kb) {
        const int buf = kb & 1;
        half8 nah, nal, nwh, nwl;
        if (kb+1 < NT) load_tile((kb+1)*32, nah, nal, nwh, nwl);
        __syncthreads();
        const char* bs = smem + buf*20480;
        const _Float16* LAh = (const _Float16*)bs;
        const _Float16* LAl = (const _Float16*)(bs +  5120);
        const _Float16* LBh = (const _Float16*)(bs + 10240);
        const _Float16* LBl = (const _Float16*)(bs + 15360);
        half8 fah[2], fal[2], fbh[2], fbl[2];
#pragma unroll
        for (int rf=0;rf<2;++rf) {
            fah[rf] = *(const half8*)(LAh + (rh*32+rf*16+lr)*LK + kq);
            fal[rf] = *(const half8*)(LAl + (rh*32+rf*16+lr)*LK + kq);
        }
#pragma unroll
        for (int cf=0;cf<2;++cf) {
            fbh[cf] = *(const half8*)(LBh + (ch*32+cf*16+lr)*LK + kq);
            fbl[cf] = *(const half8*)(LBl + (ch*32+cf*16+lr)*LK + kq);
        }
#pragma unroll
        for (int cf=0;cf<2;++cf)
#pragma unroll
            for (int rf=0;rf<2;++rf) {
                am[rf][cf] = __builtin_amdgcn_mfma_f32_16x16x32_f16(fah[rf], fbh[cf], am[rf][cf],0,0,0);
                ax[rf][cf] = __builtin_amdgcn_mfma_f32_16x16x32_f16(fah[rf], fbl[cf], ax[rf][cf],0,0,0);
                ax[rf][cf] = __builtin_amdgcn_mfma_f32_16x16x32_f16(fal[rf], fbh[cf], ax[rf][cf],0,0,0);
            }
        if (kb+1 < NT) {
            rah=nah; ral=nal; rwh=nwh; rwl=nwl;
            store_tile((kb+1)&1);
        }
    }

#pragma unroll
    for (int cf=0;cf<2;++cf) {
        int col = C0 + ch*32 + cf*16 + lr;
        float bcol = bias[col];
#pragma unroll
        for (int rf=0;rf<2;++rf)
#pragma unroll
            for (int q=0;q<4;++q) {
                size_t row = R0 + rh*32 + rf*16 + ((lane>>4)<<2) + q;
                float v = am[rf][cf][q] + ax[rf][cf][q]*INV2K + bcol;
                if (AOUT == 0) {
                    v = fmaxf(v, 0.f);
                    _Float16 h,l; splitf(v,h,l);
                    Oh[row*NCOL + col] = h;
                    Ol[row*NCOL + col] = l;
                } else {
                    Of[row*NCOL + col] = tanhf(v);
                }
            }
    }
}

// ---------------------------------------------------------------------------
// Persistent recurrence chunk. 256 blocks x 512 thr, 1 block/CU.
// 8 panels (128 rows) x 32 col-slices (32 fs cols). panel = XCC_ID;
// cs = per-XCD ticket. W1 slice LDS-resident; W2 L2-resident (2 MB/XCD).
// State: write-once rings, plain cached loads/stores. Barrier: 32 arrivals,
// AGENT relaxed atomics, bounded spin.
// ---------------------------------------------------------------------------
struct PArgs {
    const _Float16 *XeH, *XeL;
    _Float16 *EmH, *EmL;
    const _Float16 *W1h, *W1l, *W2h, *W2l;
    const float *b1, *b2, *wz, *noise;
    _Float16 *h1rH, *h1rL, *h2rH, *h2rL;  // rings [(CH+1)][BH]
    unsigned *zr;                          // ring  [(CH+1)][NB]
    float *c1g, *c2g;                      // [BH]
    unsigned *ctr;                         // [NCHUNK][CH*2][8]
    unsigned *tick;                        // [NCHUNK][8]
    int chunk;
};

__device__ __forceinline__ void xbarrier(unsigned* c, int tid)
{
    __syncthreads();   // s_waitcnt vmcnt(0) before s_barrier drains stores
    if (tid == 0) {
        __hip_atomic_fetch_add(c, 1u, __ATOMIC_RELAXED, __HIP_MEMORY_SCOPE_AGENT);
        int guard = 0;
        while (__hip_atomic_load(c, __ATOMIC_RELAXED, __HIP_MEMORY_SCOPE_AGENT) < 32u
               && guard < (1<<16)) {
            __builtin_amdgcn_s_sleep(2);
            ++guard;
        }
    }
    __syncthreads();
}

__global__ __launch_bounds__(512, 1)
void hm_pers_k(PArgs a)
{
    extern __shared__ __align__(16) char smem[];

    const int tid = threadIdx.x, wv = tid>>6, lane = tid&63;

    // ---- XCD-grounded panel/cs assignment ----
    unsigned* pan_sh = (unsigned*)(smem + PAN_OFF);
    if (tid == 0) {
        unsigned xcc;
        asm volatile("s_getreg_b32 %0, hwreg(HW_REG_XCC_ID)" : "=s"(xcc));
        xcc &= 7u;
        unsigned slot = __hip_atomic_fetch_add(a.tick + a.chunk*8 + xcc, 1u,
                          __ATOMIC_RELAXED, __HIP_MEMORY_SCOPE_AGENT);
        pan_sh[0] = xcc;
        pan_sh[1] = slot & 31u;
    }
    __syncthreads();
    const int panel = pan_sh[0], cs = pan_sh[1];

    const int rg = wv & 3, cg = wv >> 2;          // wave: rows rg*32, fs-cols cg*16
    const int lr = lane & 15, kq = (lane>>4) << 3;
    const int R0 = panel * 128;
    const int j0h = cs * 8;                       // hidden cols [j0h, j0h+8)
    const int srow = tid >> 2, seg = tid & 3;     // A staging: 128 rows x 4 segs of 8
    const size_t arbase = (size_t)(R0 + srow) * HID;
    const bool do_z = (cs == 0);

    // lane's fs column
    const int fcl  = cg*16 + lr;                  // 0..31
    const int gate = fcl >> 3;
    const int jc   = fcl & 7;
    const float bv1 = a.b1[gate*256 + j0h + jc];
    const float bv2 = a.b2[gate*256 + j0h + jc];

    // W2 staging role (tid < 256)
    const int hl2 = (tid >= 128) & 1;
    const int tt2 = tid & 127;
    const int fc2 = tt2 >> 2, sg2 = tt2 & 3;
    const _Float16* W2src = hl2 ? a.W2l : a.W2h;
    const size_t w2base = (size_t)((fc2>>3)*256 + j0h + (fc2&7))*512 + sg2*8;

    // ---- W1 slice -> LDS (once per chunk); 16-B chunks: 2 x 32cols x 96 ----
#pragma unroll
    for (int it = 0; it < 12; ++it) {
        int idx = it*512 + tid;                   // 0..6143 half8s
        int hl  = idx >= 3072;
        int e   = idx - hl*3072;
        int fc  = e / 96;
        int ks  = e - fc*96;                      // f16 offset ks*8, byte ks*16
        const _Float16* src = (hl ? a.W1l : a.W1h)
            + (size_t)((fc>>3)*256 + j0h + (fc&7))*768 + ks*8;
        *(half8*)(smem + (hl ? W1L_OFF : W1H_OFF) + (fc*LK1 + ks*8)*2)
            = *(const half8*)src;
    }
    __syncthreads();

    // update mapping: 128 rows x 8 cols, 2 cols/thread
    const int urow = tid >> 2, ujj = (tid & 3)*2;
    const size_t ubase = (size_t)(R0 + urow)*HID + j0h + ujj;

    float c1s[2], c2s[2];
    {
        float2 cv1 = *(const float2*)(a.c1g + ubase);
        float2 cv2 = *(const float2*)(a.c2g + ubase);
        c1s[0]=cv1.x; c1s[1]=cv1.y; c2s[0]=cv2.x; c2s[1]=cv2.y;
    }

    float* ex = (float*)(smem + EX_OFF);          // [4][128][9] f32 overlay

#pragma unroll 1
    for (int s = 0; s < CH; ++s) {
        const int t = a.chunk*CH + s;
        const _Float16* h1cH = a.h1rH + (size_t)s*BH;
        const _Float16* h1cL = a.h1rL + (size_t)s*BH;
        _Float16*       h1nH = a.h1rH + (size_t)(s+1)*BH;
        _Float16*       h1nL = a.h1rL + (size_t)(s+1)*BH;
        const _Float16* h2cH = a.h2rH + (size_t)s*BH;
        const _Float16* h2cL = a.h2rL + (size_t)s*BH;
        _Float16*       h2nH = a.h2rH + (size_t)(s+1)*BH;
        _Float16*       h2nL = a.h2rL + (size_t)(s+1)*BH;
        const unsigned* zc = a.zr + (size_t)s*NB;
        unsigned*       zn = a.zr + (size_t)(s+1)*NB;
        const _Float16* xeh = a.XeH + (size_t)t*BH;
        const _Float16* xel = a.XeL + (size_t)t*BH;

        // ================ phase 1: fs1 = [h1 | z*h2 | xe] @ W1 (LDS) ========
        const unsigned zrv = zc[R0+srow];
        f32x4 am[2], ax[2];
        am[0]=(f32x4)0.f; am[1]=(f32x4)0.f; ax[0]=(f32x4)0.f; ax[1]=(f32x4)0.f;
        float zacc = 0.f;
        half8 rAh[2], rAl[2], rW[2];

        auto p1_load = [&](int kt, int sl){
            int kg = kt*32 + seg*8;
            half8 hv, lv;
            if (kg < 256)      { hv = *(const half8*)(h1cH + arbase + kg);
                                 lv = *(const half8*)(h1cL + arbase + kg); }
            else if (kg < 512) {
                if (zrv) { hv = *(const half8*)(h2cH + arbase + (kg-256));
                           lv = *(const half8*)(h2cL + arbase + (kg-256)); }
                else     { hv = half8{}; lv = half8{}; }
            } else             { hv = *(const half8*)(xeh + arbase + (kg-512));
                                 lv = *(const half8*)(xel + arbase + (kg-512)); }
            rAh[sl]=hv; rAl[sl]=lv;
        };
        auto stgA = [&](int buf, int sl){
            *(half8*)(smem + AB_OFF + buf*20480         + (srow*LK + seg*8)*2) = rAh[sl];
            *(half8*)(smem + AB_OFF + buf*20480 + 10240 + (srow*LK + seg*8)*2) = rAl[sl];
        };
        auto cmp1 = [&](int buf, int kt){
            const _Float16* LAh = (const _Float16*)(smem + AB_OFF + buf*20480);
            const _Float16* LAl = (const _Float16*)(smem + AB_OFF + buf*20480 + 10240);
            const int bo = fcl*LK1 + kt*32 + kq;
            half8 fbh = *(const half8*)((const _Float16*)(smem + W1H_OFF) + bo);
            half8 fbl = *(const half8*)((const _Float16*)(smem + W1L_OFF) + bo);
#pragma unroll
            for (int rf=0; rf<2; ++rf) {
                const int ao = (rg*32 + rf*16 + lr)*LK + kq;
                half8 fah = *(const half8*)(LAh + ao);
                half8 fal = *(const half8*)(LAl + ao);
                am[rf] = __builtin_amdgcn_mfma_f32_16x16x32_f16(fah, fbh, am[rf],0,0,0);
                ax[rf] = __builtin_amdgcn_mfma_f32_16x16x32_f16(fah, fbl, ax[rf],0,0,0);
                ax[rf] = __builtin_amdgcn_mfma_f32_16x16x32_f16(fal, fbh, ax[rf],0,0,0);
            }
            if (do_z) {
#pragma unroll
                for (int i=0;i<8;++i) {
                    float av = (float)LAh[srow*LK + seg*8 + i]
                             + (float)LAl[srow*LK + seg*8 + i]*INV2K;
                    zacc = fmaf(av, a.wz[kt*32 + seg*8 + i], zacc);
                }
            }
        };

        p1_load(0,0); p1_load(1,1);
        stgA(0,0);
#pragma unroll
        for (int kt = 0; kt < 24; ++kt) {
            if (kt+2 < 24) p1_load(kt+2, kt&1);
            __syncthreads();
            cmp1(kt&1, kt);
            if (kt+1 < 24) stgA((kt+1)&1, (kt+1)&1);
        }
        __syncthreads();

        // fs1 -> ex (activated); ex overlays A buf0
#pragma unroll
        for (int rf=0; rf<2; ++rf)
#pragma unroll
            for (int q=0;q<4;++q) {
                float v = am[rf][q] + ax[rf][q]*INV2K + bv1;
                v = (gate<3) ? sigf(v) : tanhf(v);
                int row = rg*32 + rf*16 + ((lane>>4)<<2) + q;
                ex[(gate*128 + row)*9 + jc] = v;
            }
        if (do_z) {
            float sum = zacc;
            sum += __shfl_xor(sum, 1);
            sum += __shfl_xor(sum, 2);
            if (seg == 0) {
                float fsz = sum + a.b1[1024];
                float zh = fminf(fmaxf((0.1f*fsz + 1.f)*0.5f, 0.05f), 0.95f);
                unsigned zv = (a.noise[(size_t)t*NB + R0+srow] < zh) ? 1u : 0u;
                zn[R0+srow] = zv;
                if (s == CH-1) a.zr[R0+srow] = zv;
            }
        }
        __syncthreads();
        {
            H2U hh, hl;
#pragma unroll
            for (int q=0;q<2;++q) {
                float f0 = ex[(0*128+urow)*9 + ujj + q];
                float i0 = ex[(1*128+urow)*9 + ujj + q];
                float o0 = ex[(2*128+urow)*9 + ujj + q];
                float g0 = ex[(3*128+urow)*9 + ujj + q];
                float cn = f0*c1s[q] + i0*g0;
                c1s[q] = cn;
                float hv = o0*tanhf(cn);
                _Float16 h,l; splitf(hv,h,l); hh.h[q]=h; hl.h[q]=l;
            }
            *(unsigned*)(h1nH + ubase) = hh.u;
            *(unsigned*)(h1nL + ubase) = hl.u;
            if (s == CH-1) {
                *(unsigned*)(a.h1rH + ubase) = hh.u;
                *(unsigned*)(a.h1rL + ubase) = hl.u;
            }
        }
        xbarrier(a.ctr + ((size_t)(a.chunk*CH + s)*2 + 0)*8 + panel, tid);

        // ================ phase 2: fs2 = [h2 | z1n*h1n] @ W2 (L2) ===========
        const unsigned zrv2 = zn[R0+srow];
        am[0]=(f32x4)0.f; am[1]=(f32x4)0.f; ax[0]=(f32x4)0.f; ax[1]=(f32x4)0.f;

        auto p2_load = [&](int kt, int sl){
            int kg = kt*32 + seg*8;
            half8 hv, lv;
            if (kg < 256)      { hv = *(const half8*)(h2cH + arbase + kg);
                                 lv = *(const half8*)(h2cL + arbase + kg); }
            else {
                if (zrv2) { hv = *(const half8*)(h1nH + arbase + (kg-256));
                            lv = *(const half8*)(h1nL + arbase + (kg-256)); }
                else      { hv = half8{}; lv = half8{}; }
            }
            rAh[sl]=hv; rAl[sl]=lv;
            if (tid < 256) rW[sl] = *(const half8*)(W2src + w2base + kt*32);
        };
        auto stg2 = [&](int buf, int sl){
            *(half8*)(smem + AB_OFF + buf*20480         + (srow*LK + seg*8)*2) = rAh[sl];
            *(half8*)(smem + AB_OFF + buf*20480 + 10240 + (srow*LK + seg*8)*2) = rAl[sl];
            if (tid < 256)
                *(half8*)(smem + W2_OFF + buf*5120 + hl2*2560 + (fc2*LK + sg2*8)*2) = rW[sl];
        };
        auto cmp2 = [&](int buf){
            const _Float16* LAh = (const _Float16*)(smem + AB_OFF + buf*20480);
            const _Float16* LAl = (const _Float16*)(smem + AB_OFF + buf*20480 + 10240);
            const int bo = fcl*LK + kq;
            half8 fbh = *(const half8*)((const _Float16*)(smem + W2_OFF + buf*5120) + bo);
            half8 fbl = *(const half8*)((const _Float16*)(smem + W2_OFF + buf*5120 + 2560) + bo);
#pragma unroll
            for (int rf=0; rf<2; ++rf) {
                const int ao = (rg*32 + rf*16 + lr)*LK + kq;
                half8 fah = *(const half8*)(LAh + ao);
                half8 fal = *(const half8*)(LAl + ao);
                am[rf] = __builtin_amdgcn_mfma_f32_16x16x32_f16(fah, fbh, am[rf],0,0,0);
                ax[rf] = __builtin_amdgcn_mfma_f32_16x16x32_f16(fah, fbl, ax[rf],0,0,0);
                ax[rf] = __builtin_amdgcn_mfma_f32_16x16x32_f16(fal, fbh, ax[rf],0,0,0);
            }
        };

        p2_load(0,0); p2_load(1,1);
        stg2(0,0);
#pragma unroll
        for (int kt = 0; kt < 16; ++kt) {
            if (kt+2 < 16) p2_load(kt+2, kt&1);
            __syncthreads();
            cmp2(kt&1);
            if (kt+1 < 16) stg2((kt+1)&1, (kt+1)&1);
        }
        __syncthreads();

#pragma unroll
        for (int rf=0; rf<2; ++rf)
#pragma unroll
            for (int q=0;q<4;++q) {
                float v = am[rf][q] + ax[rf][q]*INV2K + bv2;
                v = (gate<3) ? sigf(v) : tanhf(v);
                int row = rg*32 + rf*16 + ((lane>>4)<<2) + q;
                ex[(gate*128 + row)*9 + jc] = v;
            }
        __syncthreads();
        {
            unsigned zun = zn[R0+urow];
            H2U hh, hl;
#pragma unroll
            for (int q=0;q<2;++q) {
                float f0 = ex[(0*128+urow)*9 + ujj + q];
                float i0 = ex[(1*128+urow)*9 + ujj + q];
                float o0 = ex[(2*128+urow)*9 + ujj + q];
                float g0 = ex[(3*128+urow)*9 + ujj + q];
                float cn = zun ? (f0*c2s[q] + i0*g0) : c2s[q];
                c2s[q] = cn;
                float hv = o0*tanhf(cn);
                _Float16 h,l; splitf(hv,h,l); hh.h[q]=h; hl.h[q]=l;
            }
            *(unsigned*)(h2nH + ubase) = hh.u;
            *(unsigned*)(h2nL + ubase) = hl.u;
            *(unsigned*)(a.EmH + (size_t)t*BH + ubase) = hh.u;
            *(unsigned*)(a.EmL + (size_t)t*BH + ubase) = hl.u;
            if (s == CH-1) {
                *(unsigned*)(a.h2rH + ubase) = hh.u;
                *(unsigned*)(a.h2rL + ubase) = hl.u;
            }
        }
        xbarrier(a.ctr + ((size_t)(a.chunk*CH + s)*2 + 1)*8 + panel, tid);
    }

    // carry c across chunk boundary
    *(float2*)(a.c1g + ubase) = float2{c1s[0], c1s[1]};
    *(float2*)(a.c2g + ubase) = float2{c2s[0], c2s[1]};
}

// ---------------------------------------------------------------------------
extern "C" void kernel_launch(void* const* d_in, const int* in_sizes, int n_in,
                              void* d_out, int out_size, void* d_ws, size_t ws_size,
                              hipStream_t stream)
{
    const float* x     = (const float*)d_in[0];
    const float* n1    = (const float*)d_in[1];
    const float* We1   = (const float*)d_in[3];
    const float* be1   = (const float*)d_in[4];
    const float* We2   = (const float*)d_in[5];
    const float* be2   = (const float*)d_in[6];
    const float* U11_1 = (const float*)d_in[7];
    const float* U21_1 = (const float*)d_in[8];
    const float* W01_1 = (const float*)d_in[9];
    const float* b1    = (const float*)d_in[10];
    const float* U11_2 = (const float*)d_in[11];
    const float* W01_2 = (const float*)d_in[12];
    const float* b2    = (const float*)d_in[13];
    const float* Wh    = (const float*)d_in[14];
    const float* bh    = (const float*)d_in[15];
    const float* Wp    = (const float*)d_in[16];
    const float* bp_   = (const float*)d_in[17];
    float* out = (float*)d_out;

    char* p = (char*)d_ws;
    auto alloc = [&](size_t bytes){ char* q = p; p += (bytes + 255) & ~(size_t)255; return q; };
    _Float16* XeH  = (_Float16*)alloc((size_t)NSTEP*BH*2);
    _Float16* XeL  = (_Float16*)alloc((size_t)NSTEP*BH*2);
    _Float16* EmH  = (_Float16*)alloc((size_t)NSTEP*BH*2);
    _Float16* EmL  = (_Float16*)alloc((size_t)NSTEP*BH*2);
    _Float16* Wt1h = (_Float16*)alloc((size_t)1024*768*2);
    _Float16* Wt1l = (_Float16*)alloc((size_t)1024*768*2);
    _Float16* Wt2h = (_Float16*)alloc((size_t)1024*512*2);
    _Float16* Wt2l = (_Float16*)alloc((size_t)1024*512*2);
    _Float16* We1h = (_Float16*)alloc(256*256*2);
    _Float16* We1l = (_Float16*)alloc(256*256*2);
    _Float16* We2h = (_Float16*)alloc(256*256*2);
    _Float16* We2l = (_Float16*)alloc(256*256*2);
    _Float16* Whh  = (_Float16*)alloc(256*256*2);
    _Float16* Whl  = (_Float16*)alloc(256*256*2);
    _Float16* Wph  = (_Float16*)alloc(64*256*2);
    _Float16* Wpl  = (_Float16*)alloc(64*256*2);
    float*    wz1  = (float*)alloc(768*4);
    _Float16* h1rH = (_Float16*)alloc((size_t)(CH+1)*BH*2);
    _Float16* h1rL = (_Float16*)alloc((size_t)(CH+1)*BH*2);
    _Float16* h2rH = (_Float16*)alloc((size_t)(CH+1)*BH*2);
    _Float16* h2rL = (_Float16*)alloc((size_t)(CH+1)*BH*2);
    unsigned* zr   = (unsigned*)alloc((size_t)(CH+1)*NB*4);
    float*    c1g  = (float*)alloc((size_t)BH*4);
    float*    c2g  = (float*)alloc((size_t)BH*4);
    unsigned* ctr  = (unsigned*)alloc((size_t)NCHUNK*CH*2*8*4);
    unsigned* tick = (unsigned*)alloc((size_t)NCHUNK*8*4);
    if (ws_size < (size_t)(p - (char*)d_ws)) return;

    _Float16* TmpH = EmH; _Float16* TmpL = EmL;   // encoder temp (Em dead then)
    _Float16* TpH  = XeH; _Float16* TpL  = XeL;   // head temp (Xe dead then)

    // ---- prep ----
    wsplit_k<<<dim3(3072), 256, 0, stream>>>(W01_1, U21_1, U11_1, 768, 1024, 1025, 256, 512, Wt1h, Wt1l);
    wsplit_k<<<dim3(2048), 256, 0, stream>>>(W01_2, U11_2, nullptr, 512, 1024, 1025, 256, 512, Wt2h, Wt2l);
    wsplit_k<<<dim3(256),  256, 0, stream>>>(We1, nullptr, nullptr, 256, 256, 256, 256, 256, We1h, We1l);
    wsplit_k<<<dim3(256),  256, 0, stream>>>(We2, nullptr, nullptr, 256, 256, 256, 256, 256, We2h, We2l);
    wsplit_k<<<dim3(256),  256, 0, stream>>>(Wh,  nullptr, nullptr, 256, 256, 256, 256, 256, Whh,  Whl);
    wsplit_k<<<dim3(64),   256, 0, stream>>>(Wp,  nullptr, nullptr, 256, 64, 64, 256, 256, Wph, Wpl);
    wz_k<<<dim3(3), 256, 0, stream>>>(W01_1, U21_1, U11_1, wz1);
    init_k<<<dim3(1024), 256, 0, stream>>>(h1rH, h1rL, h2rH, h2rL, c1g, c2g, zr);
    (void)hipMemsetAsync(ctr, 0, (size_t)NCHUNK*CH*2*8*4, stream);
    (void)hipMemsetAsync(tick, 0, (size_t)NCHUNK*8*4, stream);

    // ---- encoder: xe = relu(relu(x@We1)@We2) -> Xe ----
    for (int c = 0; c < 8; ++c) {
        size_t ro = (size_t)c*32*BH;
        gemm_t<0,0,256><<<dim3(512,4), 256, 0, stream>>>(
            x + ro, nullptr, nullptr, We1h, We1l, be1, TmpH, TmpL, nullptr);
        gemm_t<1,0,256><<<dim3(512,4), 256, 0, stream>>>(
            nullptr, TmpH, TmpL, We2h, We2l, be2, XeH + ro, XeL + ro, nullptr);
    }

    // ---- recurrence: 8 persistent chunks ----
    (void)hipFuncSetAttribute((const void*)hm_pers_k,
        hipFuncAttributeMaxDynamicSharedMemorySize, SEQ_SMEM);
    PArgs pa;
    pa.XeH = XeH; pa.XeL = XeL; pa.EmH = EmH; pa.EmL = EmL;
    pa.W1h = Wt1h; pa.W1l = Wt1l; pa.W2h = Wt2h; pa.W2l = Wt2l;
    pa.b1 = b1; pa.b2 = b2; pa.wz = wz1; pa.noise = n1;
    pa.h1rH = h1rH; pa.h1rL = h1rL; pa.h2rH = h2rH; pa.h2rL = h2rL;
    pa.zr = zr; pa.c1g = c1g; pa.c2g = c2g; pa.ctr = ctr; pa.tick = tick;
    for (int c = 0; c < NCHUNK; ++c) {
        pa.chunk = c;
        void* kargs[] = { (void*)&pa };
        (void)hipLaunchCooperativeKernel((const void*)hm_pers_k, dim3(256), dim3(512),
                                         kargs, SEQ_SMEM, stream);
    }

    // ---- head: out = tanh(relu(emb@Wh)@Wp) ----
    for (int c = 0; c < 8; ++c) {
        size_t ro = (size_t)c*32*BH;
        gemm_t<1,0,256><<<dim3(512,4), 256, 0, stream>>>(
            nullptr, EmH + ro, EmL + ro, Whh, Whl, bh, TpH, TpL, nullptr);
        gemm_t<1,1,64><<<dim3(512,1), 256, 0, stream>>>(
            nullptr, TpH, TpL, Wph, Wpl, bp_, nullptr, nullptr,
            out + (size_t)c*32*NB*64);
    }
}